// Round 4
// baseline (130.590 us; speedup 1.0000x reference)
//
#include <hip/hip_runtime.h>

// ---------- helpers ----------
static __device__ __forceinline__ unsigned short f2bf(float f) {
    unsigned int x = __float_as_uint(f);
    unsigned int lsb = (x >> 16) & 1u;
    x += 0x7fffu + lsb;                 // round-to-nearest-even
    return (unsigned short)(x >> 16);
}

typedef __attribute__((ext_vector_type(8))) short short8;    // 8 bf16 = 4 VGPRs (MFMA A/B frag)
typedef __attribute__((ext_vector_type(4))) float floatx4;   // MFMA C/D frag

static __device__ __forceinline__ short8 ldg8(const unsigned short* p) {
    short8 v; __builtin_memcpy(&v, p, 16); return v;
}

// ======================================================================
// FRAGMENT-MAJOR WEIGHT LAYOUT (16x16x32 bf16), unchanged:
//   element (n, k) -> group g=n>>4, fr=n&15, kc=k>>5, q4=(k>>3)&3, j=k&7
//   offset = (g*8 + kc)*512 + (q4*16 + fr)*8 + j
// ======================================================================

// ---------- repack: weights + biases ONLY (unchanged from round 3) ----------
__global__ __launch_bounds__(256) void repack_w(
    const float* e2p_Wq, const float* e2p_bq,
    const float* e2p_Wk, const float* e2p_bk,
    const float* e2p_Wv, const float* e2p_bv,
    const float* e2p_Wo, const float* e2p_bo,
    const float* p2e_Wq, const float* p2e_bq,
    const float* p2e_Wk, const float* p2e_bk,
    const float* p2e_Wv, const float* p2e_bv,
    const float* p2e_Wo, const float* p2e_bo,
    unsigned short* Wpack, unsigned short* Wopack, float* bias_pack, float* bias2)
{
    const int bid = blockIdx.x, tid = threadIdx.x;

    if (bid < 192) {
        int idx = bid * 256 + tid;
        int inp = idx / 24576, r = idx % 24576;
        int n = (r & 15) | ((r >> 9) << 4);              // 0..767
        int k8 = (r >> 4) & 31;
        int kc = k8 >> 2, q4 = k8 & 3, kb = k8 * 8;
        int proj = n / 256, h = (n % 256) / 32, e = n % 32;
        const float* W;
        if (inp == 0) W = (proj == 0) ? e2p_Wq : (proj == 1) ? p2e_Wk : p2e_Wv;
        else          W = (proj == 0) ? p2e_Wq : (proj == 1) ? e2p_Wk : e2p_Wv;
        unsigned short o[8];
        #pragma unroll
        for (int j = 0; j < 8; ++j) o[j] = f2bf(W[h * 8192 + (kb + j) * 32 + e]);
        __builtin_memcpy(Wpack + inp * 196608 + ((n >> 4) * 8 + kc) * 512 + (q4 * 16 + (n & 15)) * 8, o, 16);
        return;
    }
    if (bid < 256) {
        int i2 = (bid - 192) * 256 + tid;
        int dir = i2 / 8192, r = i2 % 8192;
        int n = (r & 15) | ((r >> 9) << 4);              // 0..255
        int k8 = (r >> 4) & 31;
        int kc = k8 >> 2, q4 = k8 & 3, kb = k8 * 8;
        const float* Wo = dir ? p2e_Wo : e2p_Wo;
        unsigned short o[8];
        #pragma unroll
        for (int j = 0; j < 8; ++j) o[j] = f2bf(Wo[(kb + j) * 256 + n]);
        __builtin_memcpy(Wopack + dir * 65536 + ((n >> 4) * 8 + kc) * 512 + (q4 * 16 + (n & 15)) * 8, o, 16);
        return;
    }
    {
        int idx = (bid - 256) * 256 + tid;   // 0..2047
        if (idx < 1536) {
            int inp = idx / 768, n = idx % 768;
            int proj = n / 256, he = n % 256;
            const float* bsrc;
            if (inp == 0) bsrc = (proj == 0) ? e2p_bq : (proj == 1) ? p2e_bk : p2e_bv;
            else          bsrc = (proj == 0) ? p2e_bq : (proj == 1) ? e2p_bk : e2p_bv;
            bias_pack[idx] = bsrc[he];
        } else {
            int j = idx - 1536;
            int dir = j / 256, n = j % 256;
            bias2[j] = (dir == 0 ? e2p_bo : p2e_bo)[n];
        }
    }
}

// ---------- fully fused, TWO-TILE PIPELINED version ----------
// Grid 256 blocks = exactly 1/CU (LDS 149 KB forces 1 resident anyway); each
// block processes two adjacent 32-row s-tiles in sequence. Tile B's X input is
// prefetched into REGISTERS during tile A's scores/softmax/PV (issue-early /
// write-late), and written to the X LDS regions after barrier(2), where tile
// A's X is dead. Tile B therefore starts compute with zero staging latency,
// and the old block-round-2 (staging stall + drain gap) disappears.
//
// Barrier ordering per tile (ALL cross-tile/c ross-wave LDS reuse is
// barrier-protected; the only non-barrier reuse is the round-3-proven
// same-wave P-over-Kw data-dependence):
//   (2) post-PV: X(t) + scratch dead -> write X(t+1) + att tile As(t)
//   (3) As(t)+X(t+1) complete -> outproj reads As(t)
//   (4) outproj As reads done -> next tile may overwrite scratch (As aliases it)
//
// LDS map (shorts), total 74496 = 148,992 B:
//   [0,8448)        Xq  [32][264]
//   [8448,25344)    Xkv [64][264]
//   [25344,74496)   per-wave scratch, 6144 each: Qw[32][40] / Kw[64][40] / Vt[32][72]
//                   As [32][264] (8448) aliases the scratch region after PV.
#define XSTR 264
#define KSTR 40
#define PSTR 72
#define VTSTR 72
#define XKV_OFF 8448
#define SCR_OFF 25344
#define SCR_SZ 6144
__global__ __launch_bounds__(512, 2) void fused_attn(
    const float* __restrict__ eeg, const float* __restrict__ pps,
    const unsigned short* __restrict__ Wpack, const float* __restrict__ biasP,
    const unsigned short* __restrict__ Wopack, const float* __restrict__ bias2,
    float* __restrict__ out)
{
    __shared__ __align__(16) unsigned short smem[74496];   // 148992 B
    unsigned short* Xq  = smem;
    unsigned short* Xkv = smem + XKV_OFF;

    const int b = blockIdx.y, dir = blockIdx.z;
    const int kvinp = 1 - dir;
    const int tid = threadIdx.x;
    const int lane = tid & 63;
    const int wv = tid >> 6;                    // head index 0..7
    const int fr = lane & 15, q4 = lane >> 4;

    unsigned short* Qw = smem + SCR_OFF + wv * SCR_SZ;   // [32][40]
    unsigned short* Kw = Qw + 1280;                      // [64][40]; P [32][72] aliases later
    unsigned short* Vt = Qw + 3840;                      // [32][72]
    unsigned short (*As)[XSTR] = (unsigned short(*)[XSTR])(smem + SCR_OFF);

    const float* Xqsrc  = dir ? pps : eeg;
    const float* Xkvsrc = dir ? eeg : pps;

    // per-wave bias scalars (col = j*16+fr)
    float bqq[2], bkk[2], bvv[2], bj2[2];
    #pragma unroll
    for (int j = 0; j < 2; ++j) {
        bqq[j] = biasP[dir * 768 + wv * 32 + j * 16 + fr];
        bkk[j] = biasP[kvinp * 768 + 256 + wv * 32 + j * 16 + fr];
        bvv[j] = biasP[kvinp * 768 + 512 + wv * 32 + j * 16 + fr];
        bj2[j] = bias2[dir * 256 + wv * 32 + j * 16 + fr];
    }

    const unsigned short* WB = Wpack + (long)kvinp * 196608 + lane * 8;
    const unsigned short* WQ = Wpack + (long)dir * 196608 + lane * 8;
    const unsigned short* Wo = Wopack + dir * 65536 + lane * 8;

    const int sA = blockIdx.x * 64;
    const int sB = sA + 32;

    // ---- stage tile A's X (fp32 -> bf16), coalesced 128B per thread ----
    {
        const int r = tid >> 3, seg = (tid & 7) * 32;    // r 0..63
        const int p = sA - 15 + r;
        unsigned short o[32];
        if (p >= 0 && p < 2048) {
            float v[32];
            __builtin_memcpy(v, Xkvsrc + ((long)b * 2048 + p) * 256 + seg, 128);
            #pragma unroll
            for (int j = 0; j < 32; ++j) o[j] = f2bf(v[j]);
        } else {
            #pragma unroll
            for (int j = 0; j < 32; ++j) o[j] = 0;       // zero-pad BEFORE projection
        }
        __builtin_memcpy(&Xkv[r * XSTR + seg], o, 64);
        if (tid < 256) {                                 // Xq rows 0..31, always in-bounds
            float v[32];
            __builtin_memcpy(v, Xqsrc + ((long)b * 2048 + sA + r) * 256 + seg, 128);
            unsigned short o2[32];
            #pragma unroll
            for (int j = 0; j < 32; ++j) o2[j] = f2bf(v[j]);
            __builtin_memcpy(&Xq[r * XSTR + seg], o2, 64);
        }
    }
    __syncthreads();   // (1) tile A staging complete

    auto body = [&](int s0, bool PRE, int ns0) {
        // ---- Q slice: [32 s][32 e] = Xq @ Wq(head) ----
        floatx4 qacc[2][2] = {};
        #pragma unroll
        for (int kc = 0; kc < 8; ++kc) {
            short8 a0 = *(const short8*)&Xq[(fr) * XSTR + kc * 32 + q4 * 8];
            short8 a1 = *(const short8*)&Xq[(16 + fr) * XSTR + kc * 32 + q4 * 8];
            #pragma unroll
            for (int j = 0; j < 2; ++j) {
                short8 bw = ldg8(WQ + ((2 * wv + j) * 8 + kc) * 512);
                qacc[0][j] = __builtin_amdgcn_mfma_f32_16x16x32_bf16(a0, bw, qacc[0][j], 0, 0, 0);
                qacc[1][j] = __builtin_amdgcn_mfma_f32_16x16x32_bf16(a1, bw, qacc[1][j], 0, 0, 0);
            }
        }
        // Q C-frags (+bias) -> dedicated Qw scratch (never overwritten this tile)
        #pragma unroll
        for (int it = 0; it < 2; ++it)
            #pragma unroll
            for (int j = 0; j < 2; ++j)
                #pragma unroll
                for (int reg = 0; reg < 4; ++reg)
                    Qw[(it * 16 + q4 * 4 + reg) * KSTR + j * 16 + fr] = f2bf(qacc[it][j][reg] + bqq[j]);

        // ---- K,V slices: [64 kv][32 e] = Xkv @ {Wk,Wv}(head), shared A-frags ----
        floatx4 kacc[4][2] = {}, vacc[4][2] = {};
        #pragma unroll
        for (int kc = 0; kc < 8; ++kc) {
            short8 ax[4];
            #pragma unroll
            for (int mi = 0; mi < 4; ++mi)
                ax[mi] = *(const short8*)&Xkv[(mi * 16 + fr) * XSTR + kc * 32 + q4 * 8];
            #pragma unroll
            for (int j = 0; j < 2; ++j) {
                short8 kb = ldg8(WB + ((16 + 2 * wv + j) * 8 + kc) * 512);
                short8 vb = ldg8(WB + ((32 + 2 * wv + j) * 8 + kc) * 512);
                #pragma unroll
                for (int mi = 0; mi < 4; ++mi) {
                    kacc[mi][j] = __builtin_amdgcn_mfma_f32_16x16x32_bf16(ax[mi], kb, kacc[mi][j], 0, 0, 0);
                    vacc[mi][j] = __builtin_amdgcn_mfma_f32_16x16x32_bf16(ax[mi], vb, vacc[mi][j], 0, 0, 0);
                }
            }
        }
        // K C-frags (+bias) -> Kw rows 0..63
        #pragma unroll
        for (int mi = 0; mi < 4; ++mi)
            #pragma unroll
            for (int j = 0; j < 2; ++j)
                #pragma unroll
                for (int reg = 0; reg < 4; ++reg)
                    Kw[(mi * 16 + q4 * 4 + reg) * KSTR + j * 16 + fr] = f2bf(kacc[mi][j][reg] + bkk[j]);
        // V C-frags (+bias) -> Vt TRANSPOSED (Vt[e][kv]); 4 regs = 8B contiguous
        #pragma unroll
        for (int mi = 0; mi < 4; ++mi)
            #pragma unroll
            for (int j = 0; j < 2; ++j) {
                unsigned short t4[4];
                #pragma unroll
                for (int reg = 0; reg < 4; ++reg) t4[reg] = f2bf(vacc[mi][j][reg] + bvv[j]);
                __builtin_memcpy(&Vt[(j * 16 + fr) * VTSTR + mi * 16 + q4 * 4], t4, 8);
            }

        // ---- PREFETCH next tile's X into registers (issue-early) ----
        // Loads fly under scores/softmax/P/PV; written to LDS after barrier(2).
        float pkv[32]; float pq[32];
        bool kv_ok = false;
        if (PRE) {
            const int r = tid >> 3, seg = (tid & 7) * 32;
            const int p = ns0 - 15 + r;
            if (p >= 0 && p < 2048) {
                kv_ok = true;
                __builtin_memcpy(pkv, Xkvsrc + ((long)b * 2048 + p) * 256 + seg, 128);
            }
            if (tid < 256)
                __builtin_memcpy(pq, Xqsrc + ((long)b * 2048 + ns0 + r) * 256 + seg, 128);
        }

        // ---- scores: S[32 s][64 kv]; band structure -> 6 of 8 MFMAs ----
        short8 aq0 = *(const short8*)&Qw[fr * KSTR + q4 * 8];
        short8 aq1 = *(const short8*)&Qw[(16 + fr) * KSTR + q4 * 8];
        floatx4 sacc[2][3] = {};
        #pragma unroll
        for (int kvt = 0; kvt < 4; ++kvt) {
            short8 bk_ = *(const short8*)&Kw[(kvt * 16 + fr) * KSTR + q4 * 8];
            if (kvt < 3) sacc[0][kvt]     = __builtin_amdgcn_mfma_f32_16x16x32_bf16(aq0, bk_, sacc[0][kvt], 0, 0, 0);
            if (kvt > 0) sacc[1][kvt - 1] = __builtin_amdgcn_mfma_f32_16x16x32_bf16(aq1, bk_, sacc[1][kvt - 1], 0, 0, 0);
        }

        // ---- band mask + softmax (row i = it*16+q4*4+reg; col jc = (it+kt)*16+fr) ----
        float sv[2][3][4];
        float rs[2][4];
        #pragma unroll
        for (int it = 0; it < 2; ++it) {
            float mx[4] = {-3.0e38f, -3.0e38f, -3.0e38f, -3.0e38f};
            #pragma unroll
            for (int kt = 0; kt < 3; ++kt)
                #pragma unroll
                for (int reg = 0; reg < 4; ++reg) {
                    int i = it * 16 + q4 * 4 + reg;
                    int jc = (it + kt) * 16 + fr;
                    int d = jc - i;
                    float x = (d >= 0 && d <= 30) ? sacc[it][kt][reg] * 0.17677669529663687f : -3.0e38f;
                    sv[it][kt][reg] = x;
                    mx[reg] = fmaxf(mx[reg], x);
                }
            #pragma unroll
            for (int off = 1; off < 16; off <<= 1)
                #pragma unroll
                for (int reg = 0; reg < 4; ++reg)
                    mx[reg] = fmaxf(mx[reg], __shfl_xor(mx[reg], off));
            float ps[4] = {};
            #pragma unroll
            for (int kt = 0; kt < 3; ++kt)
                #pragma unroll
                for (int reg = 0; reg < 4; ++reg) {
                    float e = __expf(sv[it][kt][reg] - mx[reg]);
                    sv[it][kt][reg] = e;
                    ps[reg] += e;
                }
            #pragma unroll
            for (int off = 1; off < 16; off <<= 1)
                #pragma unroll
                for (int reg = 0; reg < 4; ++reg)
                    ps[reg] += __shfl_xor(ps[reg], off);
            #pragma unroll
            for (int reg = 0; reg < 4; ++reg) rs[it][reg] = 1.0f / ps[reg];
        }

        // ---- P -> Kw-alias as [32][72] bf16 (same-wave data-dep WAR, proven r3) ----
        unsigned short* Pb = Kw;
        #pragma unroll
        for (int it = 0; it < 2; ++it)
            #pragma unroll
            for (int reg = 0; reg < 4; ++reg) {
                int i = it * 16 + q4 * 4 + reg;
                #pragma unroll
                for (int kt = 0; kt < 3; ++kt)
                    Pb[i * PSTR + (it + kt) * 16 + fr] = f2bf(sv[it][kt][reg]);
                Pb[i * PSTR + (it == 0 ? 48 : 0) + fr] = 0;
            }

        // ---- PV: O[32 s][32 e] via 8 MFMAs ----
        floatx4 oacc[2][2] = {};
        #pragma unroll
        for (int ch = 0; ch < 2; ++ch) {
            short8 ap0 = *(const short8*)&Pb[fr * PSTR + ch * 32 + q4 * 8];
            short8 ap1 = *(const short8*)&Pb[(16 + fr) * PSTR + ch * 32 + q4 * 8];
            #pragma unroll
            for (int et = 0; et < 2; ++et) {
                short8 bv = *(const short8*)&Vt[(et * 16 + fr) * VTSTR + ch * 32 + q4 * 8];
                oacc[0][et] = __builtin_amdgcn_mfma_f32_16x16x32_bf16(ap0, bv, oacc[0][et], 0, 0, 0);
                oacc[1][et] = __builtin_amdgcn_mfma_f32_16x16x32_bf16(ap1, bv, oacc[1][et], 0, 0, 0);
            }
        }

        __syncthreads();   // (2) X(t) + scratch reads done everywhere

        // ---- write next tile's X (write-late half of the prefetch) ----
        if (PRE) {
            const int r = tid >> 3, seg = (tid & 7) * 32;
            unsigned short o[32];
            if (kv_ok) {
                #pragma unroll
                for (int j = 0; j < 32; ++j) o[j] = f2bf(pkv[j]);
            } else {
                #pragma unroll
                for (int j = 0; j < 32; ++j) o[j] = 0;
            }
            __builtin_memcpy(&Xkv[r * XSTR + seg], o, 64);
            if (tid < 256) {
                unsigned short o2[32];
                #pragma unroll
                for (int j = 0; j < 32; ++j) o2[j] = f2bf(pq[j]);
                __builtin_memcpy(&Xq[r * XSTR + seg], o2, 64);
            }
        }

        // ---- att tile [32][264] over scratch region ----
        #pragma unroll
        for (int it = 0; it < 2; ++it)
            #pragma unroll
            for (int et = 0; et < 2; ++et)
                #pragma unroll
                for (int reg = 0; reg < 4; ++reg)
                    As[it * 16 + q4 * 4 + reg][wv * 32 + et * 16 + fr] = f2bf(oacc[it][et][reg] * rs[it][reg]);

        __syncthreads();   // (3) att tile + next X complete

        // ---- output projection: out[32 x 256] = att @ Wo^T + bias2 ----
        floatx4 oa[2][2] = {};
        #pragma unroll
        for (int kc = 0; kc < 8; ++kc) {
            short8 ap0 = *(const short8*)&As[fr][kc * 32 + q4 * 8];
            short8 ap1 = *(const short8*)&As[16 + fr][kc * 32 + q4 * 8];
            #pragma unroll
            for (int j = 0; j < 2; ++j) {
                short8 bw = ldg8(Wo + ((wv * 2 + j) * 8 + kc) * 512);
                oa[0][j] = __builtin_amdgcn_mfma_f32_16x16x32_bf16(ap0, bw, oa[0][j], 0, 0, 0);
                oa[1][j] = __builtin_amdgcn_mfma_f32_16x16x32_bf16(ap1, bw, oa[1][j], 0, 0, 0);
            }
        }

        float* obase = out + (long)dir * 2097152 + ((long)b * 2048 + s0) * 256;
        #pragma unroll
        for (int it = 0; it < 2; ++it)
            #pragma unroll
            for (int j = 0; j < 2; ++j)
                #pragma unroll
                for (int reg = 0; reg < 4; ++reg)
                    obase[(it * 16 + q4 * 4 + reg) * 256 + wv * 32 + j * 16 + fr] = oa[it][j][reg] + bj2[j];

        __syncthreads();   // (4) As reads done -> next tile may overwrite scratch
    };

    body(sA, true,  sB);
    body(sB, false, 0);
}

// ---------- launch ----------
extern "C" void kernel_launch(void* const* d_in, const int* in_sizes, int n_in,
                              void* d_out, int out_size, void* d_ws, size_t ws_size,
                              hipStream_t stream)
{
    float* out = (float*)d_out;

    char* ws = (char*)d_ws;
    unsigned short* Wpack   = (unsigned short*)(ws + 0);          // 786432 B (frag-major)
    unsigned short* Wopack  = (unsigned short*)(ws + 786432);     // 262144 B (frag-major)
    float*          biasP   = (float*)(ws + 1048576);             // 6144 B
    float*          bias2   = (float*)(ws + 1054720);             // 2048 B

    repack_w<<<264, 256, 0, stream>>>(
        (const float*)d_in[2],  (const float*)d_in[3],
        (const float*)d_in[4],  (const float*)d_in[5],
        (const float*)d_in[6],  (const float*)d_in[7],
        (const float*)d_in[8],  (const float*)d_in[9],
        (const float*)d_in[10], (const float*)d_in[11],
        (const float*)d_in[12], (const float*)d_in[13],
        (const float*)d_in[14], (const float*)d_in[15],
        (const float*)d_in[16], (const float*)d_in[17],
        Wpack, Wopack, biasP, bias2);

    // fully fused QKV proj + windowed attention + output proj -> d_out (fp32)
    fused_attn<<<dim3(32, 4, 2), 512, 0, stream>>>(
        (const float*)d_in[0], (const float*)d_in[1],
        Wpack, biasP, Wopack, bias2, out);
}

// Round 5
// 130.138 us; speedup vs baseline: 1.0035x; 1.0035x over previous
//
#include <hip/hip_runtime.h>

// ---------- helpers ----------
static __device__ __forceinline__ unsigned short f2bf(float f) {
    unsigned int x = __float_as_uint(f);
    unsigned int lsb = (x >> 16) & 1u;
    x += 0x7fffu + lsb;                 // round-to-nearest-even
    return (unsigned short)(x >> 16);
}

typedef __attribute__((ext_vector_type(8))) short short8;    // 8 bf16 = 4 VGPRs (MFMA A/B frag)
typedef __attribute__((ext_vector_type(4))) float floatx4;   // MFMA C/D frag

static __device__ __forceinline__ short8 ldg8(const unsigned short* p) {
    short8 v; __builtin_memcpy(&v, p, 16); return v;
}

// ======================================================================
// FRAGMENT-MAJOR WEIGHT LAYOUT (16x16x32 bf16), unchanged:
//   element (n, k) -> group g=n>>4, fr=n&15, kc=k>>5, q4=(k>>3)&3, j=k&7
//   offset = (g*8 + kc)*512 + (q4*16 + fr)*8 + j
// ======================================================================

// ---------- repack: weights + biases ONLY (unchanged) ----------
__global__ __launch_bounds__(256) void repack_w(
    const float* e2p_Wq, const float* e2p_bq,
    const float* e2p_Wk, const float* e2p_bk,
    const float* e2p_Wv, const float* e2p_bv,
    const float* e2p_Wo, const float* e2p_bo,
    const float* p2e_Wq, const float* p2e_bq,
    const float* p2e_Wk, const float* p2e_bk,
    const float* p2e_Wv, const float* p2e_bv,
    const float* p2e_Wo, const float* p2e_bo,
    unsigned short* Wpack, unsigned short* Wopack, float* bias_pack, float* bias2)
{
    const int bid = blockIdx.x, tid = threadIdx.x;

    if (bid < 192) {
        int idx = bid * 256 + tid;
        int inp = idx / 24576, r = idx % 24576;
        int n = (r & 15) | ((r >> 9) << 4);              // 0..767
        int k8 = (r >> 4) & 31;
        int kc = k8 >> 2, q4 = k8 & 3, kb = k8 * 8;
        int proj = n / 256, h = (n % 256) / 32, e = n % 32;
        const float* W;
        if (inp == 0) W = (proj == 0) ? e2p_Wq : (proj == 1) ? p2e_Wk : p2e_Wv;
        else          W = (proj == 0) ? p2e_Wq : (proj == 1) ? e2p_Wk : e2p_Wv;
        unsigned short o[8];
        #pragma unroll
        for (int j = 0; j < 8; ++j) o[j] = f2bf(W[h * 8192 + (kb + j) * 32 + e]);
        __builtin_memcpy(Wpack + inp * 196608 + ((n >> 4) * 8 + kc) * 512 + (q4 * 16 + (n & 15)) * 8, o, 16);
        return;
    }
    if (bid < 256) {
        int i2 = (bid - 192) * 256 + tid;
        int dir = i2 / 8192, r = i2 % 8192;
        int n = (r & 15) | ((r >> 9) << 4);              // 0..255
        int k8 = (r >> 4) & 31;
        int kc = k8 >> 2, q4 = k8 & 3, kb = k8 * 8;
        const float* Wo = dir ? p2e_Wo : e2p_Wo;
        unsigned short o[8];
        #pragma unroll
        for (int j = 0; j < 8; ++j) o[j] = f2bf(Wo[(kb + j) * 256 + n]);
        __builtin_memcpy(Wopack + dir * 65536 + ((n >> 4) * 8 + kc) * 512 + (q4 * 16 + (n & 15)) * 8, o, 16);
        return;
    }
    {
        int idx = (bid - 256) * 256 + tid;   // 0..2047
        if (idx < 1536) {
            int inp = idx / 768, n = idx % 768;
            int proj = n / 256, he = n % 256;
            const float* bsrc;
            if (inp == 0) bsrc = (proj == 0) ? e2p_bq : (proj == 1) ? p2e_bk : p2e_bv;
            else          bsrc = (proj == 0) ? p2e_bq : (proj == 1) ? e2p_bk : e2p_bv;
            bias_pack[idx] = bsrc[he];
        } else {
            int j = idx - 1536;
            int dir = j / 256, n = j % 256;
            bias2[j] = (dir == 0 ? e2p_bo : p2e_bo)[n];
        }
    }
}

// ---------- fully fused, two-tile pipelined + REGISTER-RESIDENT K/V WEIGHTS ----------
// Identical structure/barriers/aliasing to the passing round-4 kernel; the only
// change: the 32 K/V weight fragments (128 VGPRs) are loaded ONCE at kernel
// start and reused by both tiles. The K/V projection inner loop (the hottest
// phase: 128 MFMAs/tile) becomes pure LDS+MFMA with no global-load waits.
// LDS-bound occupancy (1 block/CU, 2 waves/SIMD) makes the VGPR budget (256)
// free — we spend it on latency removal.
#define XSTR 264
#define KSTR 40
#define PSTR 72
#define VTSTR 72
#define XKV_OFF 8448
#define SCR_OFF 25344
#define SCR_SZ 6144
__global__ __launch_bounds__(512, 2) void fused_attn(
    const float* __restrict__ eeg, const float* __restrict__ pps,
    const unsigned short* __restrict__ Wpack, const float* __restrict__ biasP,
    const unsigned short* __restrict__ Wopack, const float* __restrict__ bias2,
    float* __restrict__ out)
{
    __shared__ __align__(16) unsigned short smem[74496];   // 148992 B
    unsigned short* Xq  = smem;
    unsigned short* Xkv = smem + XKV_OFF;

    const int b = blockIdx.y, dir = blockIdx.z;
    const int kvinp = 1 - dir;
    const int tid = threadIdx.x;
    const int lane = tid & 63;
    const int wv = tid >> 6;                    // head index 0..7
    const int fr = lane & 15, q4 = lane >> 4;

    unsigned short* Qw = smem + SCR_OFF + wv * SCR_SZ;   // [32][40]
    unsigned short* Kw = Qw + 1280;                      // [64][40]; P [32][72] aliases later
    unsigned short* Vt = Qw + 3840;                      // [32][72]
    unsigned short (*As)[XSTR] = (unsigned short(*)[XSTR])(smem + SCR_OFF);

    const float* Xqsrc  = dir ? pps : eeg;
    const float* Xkvsrc = dir ? eeg : pps;

    // per-wave bias scalars (col = j*16+fr)
    float bqq[2], bkk[2], bvv[2], bj2[2];
    #pragma unroll
    for (int j = 0; j < 2; ++j) {
        bqq[j] = biasP[dir * 768 + wv * 32 + j * 16 + fr];
        bkk[j] = biasP[kvinp * 768 + 256 + wv * 32 + j * 16 + fr];
        bvv[j] = biasP[kvinp * 768 + 512 + wv * 32 + j * 16 + fr];
        bj2[j] = bias2[dir * 256 + wv * 32 + j * 16 + fr];
    }

    const unsigned short* WB = Wpack + (long)kvinp * 196608 + lane * 8;
    const unsigned short* WQ = Wpack + (long)dir * 196608 + lane * 8;
    const unsigned short* Wo = Wopack + dir * 65536 + lane * 8;

    const int sA = blockIdx.x * 64;
    const int sB = sA + 32;

    // ---- stage tile A's X (fp32 -> bf16), coalesced 128B per thread ----
    // Issued FIRST so the deep HBM loads get the memory pipe before weights.
    {
        const int r = tid >> 3, seg = (tid & 7) * 32;    // r 0..63
        const int p = sA - 15 + r;
        unsigned short o[32];
        if (p >= 0 && p < 2048) {
            float v[32];
            __builtin_memcpy(v, Xkvsrc + ((long)b * 2048 + p) * 256 + seg, 128);
            #pragma unroll
            for (int j = 0; j < 32; ++j) o[j] = f2bf(v[j]);
        } else {
            #pragma unroll
            for (int j = 0; j < 32; ++j) o[j] = 0;       // zero-pad BEFORE projection
        }
        __builtin_memcpy(&Xkv[r * XSTR + seg], o, 64);
        if (tid < 256) {                                 // Xq rows 0..31, always in-bounds
            float v[32];
            __builtin_memcpy(v, Xqsrc + ((long)b * 2048 + sA + r) * 256 + seg, 128);
            unsigned short o2[32];
            #pragma unroll
            for (int j = 0; j < 32; ++j) o2[j] = f2bf(v[j]);
            __builtin_memcpy(&Xq[r * XSTR + seg], o2, 64);
        }
    }

    // ---- PERSISTENT K/V weight fragments: 32 frags = 128 VGPRs, loaded once ----
    short8 kwf[2][8], vwf[2][8];
    #pragma unroll
    for (int j = 0; j < 2; ++j)
        #pragma unroll
        for (int kc = 0; kc < 8; ++kc) {
            kwf[j][kc] = ldg8(WB + ((16 + 2 * wv + j) * 8 + kc) * 512);
            vwf[j][kc] = ldg8(WB + ((32 + 2 * wv + j) * 8 + kc) * 512);
        }

    __syncthreads();   // (1) tile A staging complete (drains weight loads too)

    auto body = [&](int s0, bool PRE, int ns0) {
        // ---- Q slice: [32 s][32 e] = Xq @ Wq(head) ----
        floatx4 qacc[2][2] = {};
        #pragma unroll
        for (int kc = 0; kc < 8; ++kc) {
            short8 a0 = *(const short8*)&Xq[(fr) * XSTR + kc * 32 + q4 * 8];
            short8 a1 = *(const short8*)&Xq[(16 + fr) * XSTR + kc * 32 + q4 * 8];
            #pragma unroll
            for (int j = 0; j < 2; ++j) {
                short8 bw = ldg8(WQ + ((2 * wv + j) * 8 + kc) * 512);
                qacc[0][j] = __builtin_amdgcn_mfma_f32_16x16x32_bf16(a0, bw, qacc[0][j], 0, 0, 0);
                qacc[1][j] = __builtin_amdgcn_mfma_f32_16x16x32_bf16(a1, bw, qacc[1][j], 0, 0, 0);
            }
        }
        // Q C-frags (+bias) -> dedicated Qw scratch (never overwritten this tile)
        #pragma unroll
        for (int it = 0; it < 2; ++it)
            #pragma unroll
            for (int j = 0; j < 2; ++j)
                #pragma unroll
                for (int reg = 0; reg < 4; ++reg)
                    Qw[(it * 16 + q4 * 4 + reg) * KSTR + j * 16 + fr] = f2bf(qacc[it][j][reg] + bqq[j]);

        // ---- K,V slices: [64 kv][32 e] = Xkv @ {Wk,Wv}(head) — weights in regs ----
        floatx4 kacc[4][2] = {}, vacc[4][2] = {};
        #pragma unroll
        for (int kc = 0; kc < 8; ++kc) {
            short8 ax[4];
            #pragma unroll
            for (int mi = 0; mi < 4; ++mi)
                ax[mi] = *(const short8*)&Xkv[(mi * 16 + fr) * XSTR + kc * 32 + q4 * 8];
            #pragma unroll
            for (int j = 0; j < 2; ++j) {
                #pragma unroll
                for (int mi = 0; mi < 4; ++mi) {
                    kacc[mi][j] = __builtin_amdgcn_mfma_f32_16x16x32_bf16(ax[mi], kwf[j][kc], kacc[mi][j], 0, 0, 0);
                    vacc[mi][j] = __builtin_amdgcn_mfma_f32_16x16x32_bf16(ax[mi], vwf[j][kc], vacc[mi][j], 0, 0, 0);
                }
            }
        }
        // K C-frags (+bias) -> Kw rows 0..63
        #pragma unroll
        for (int mi = 0; mi < 4; ++mi)
            #pragma unroll
            for (int j = 0; j < 2; ++j)
                #pragma unroll
                for (int reg = 0; reg < 4; ++reg)
                    Kw[(mi * 16 + q4 * 4 + reg) * KSTR + j * 16 + fr] = f2bf(kacc[mi][j][reg] + bkk[j]);
        // V C-frags (+bias) -> Vt TRANSPOSED (Vt[e][kv]); 4 regs = 8B contiguous
        #pragma unroll
        for (int mi = 0; mi < 4; ++mi)
            #pragma unroll
            for (int j = 0; j < 2; ++j) {
                unsigned short t4[4];
                #pragma unroll
                for (int reg = 0; reg < 4; ++reg) t4[reg] = f2bf(vacc[mi][j][reg] + bvv[j]);
                __builtin_memcpy(&Vt[(j * 16 + fr) * VTSTR + mi * 16 + q4 * 4], t4, 8);
            }

        // ---- PREFETCH next tile's X into registers (issue-early) ----
        float pkv[32]; float pq[32];
        bool kv_ok = false;
        if (PRE) {
            const int r = tid >> 3, seg = (tid & 7) * 32;
            const int p = ns0 - 15 + r;
            if (p >= 0 && p < 2048) {
                kv_ok = true;
                __builtin_memcpy(pkv, Xkvsrc + ((long)b * 2048 + p) * 256 + seg, 128);
            }
            if (tid < 256)
                __builtin_memcpy(pq, Xqsrc + ((long)b * 2048 + ns0 + r) * 256 + seg, 128);
        }

        // ---- scores: S[32 s][64 kv]; band structure -> 6 of 8 MFMAs ----
        short8 aq0 = *(const short8*)&Qw[fr * KSTR + q4 * 8];
        short8 aq1 = *(const short8*)&Qw[(16 + fr) * KSTR + q4 * 8];
        floatx4 sacc[2][3] = {};
        #pragma unroll
        for (int kvt = 0; kvt < 4; ++kvt) {
            short8 bk_ = *(const short8*)&Kw[(kvt * 16 + fr) * KSTR + q4 * 8];
            if (kvt < 3) sacc[0][kvt]     = __builtin_amdgcn_mfma_f32_16x16x32_bf16(aq0, bk_, sacc[0][kvt], 0, 0, 0);
            if (kvt > 0) sacc[1][kvt - 1] = __builtin_amdgcn_mfma_f32_16x16x32_bf16(aq1, bk_, sacc[1][kvt - 1], 0, 0, 0);
        }

        // ---- band mask + softmax (row i = it*16+q4*4+reg; col jc = (it+kt)*16+fr) ----
        float sv[2][3][4];
        float rs[2][4];
        #pragma unroll
        for (int it = 0; it < 2; ++it) {
            float mx[4] = {-3.0e38f, -3.0e38f, -3.0e38f, -3.0e38f};
            #pragma unroll
            for (int kt = 0; kt < 3; ++kt)
                #pragma unroll
                for (int reg = 0; reg < 4; ++reg) {
                    int i = it * 16 + q4 * 4 + reg;
                    int jc = (it + kt) * 16 + fr;
                    int d = jc - i;
                    float x = (d >= 0 && d <= 30) ? sacc[it][kt][reg] * 0.17677669529663687f : -3.0e38f;
                    sv[it][kt][reg] = x;
                    mx[reg] = fmaxf(mx[reg], x);
                }
            #pragma unroll
            for (int off = 1; off < 16; off <<= 1)
                #pragma unroll
                for (int reg = 0; reg < 4; ++reg)
                    mx[reg] = fmaxf(mx[reg], __shfl_xor(mx[reg], off));
            float ps[4] = {};
            #pragma unroll
            for (int kt = 0; kt < 3; ++kt)
                #pragma unroll
                for (int reg = 0; reg < 4; ++reg) {
                    float e = __expf(sv[it][kt][reg] - mx[reg]);
                    sv[it][kt][reg] = e;
                    ps[reg] += e;
                }
            #pragma unroll
            for (int off = 1; off < 16; off <<= 1)
                #pragma unroll
                for (int reg = 0; reg < 4; ++reg)
                    ps[reg] += __shfl_xor(ps[reg], off);
            #pragma unroll
            for (int reg = 0; reg < 4; ++reg) rs[it][reg] = 1.0f / ps[reg];
        }

        // ---- P -> Kw-alias as [32][72] bf16 (same-wave data-dep WAR, proven r3) ----
        unsigned short* Pb = Kw;
        #pragma unroll
        for (int it = 0; it < 2; ++it)
            #pragma unroll
            for (int reg = 0; reg < 4; ++reg) {
                int i = it * 16 + q4 * 4 + reg;
                #pragma unroll
                for (int kt = 0; kt < 3; ++kt)
                    Pb[i * PSTR + (it + kt) * 16 + fr] = f2bf(sv[it][kt][reg]);
                Pb[i * PSTR + (it == 0 ? 48 : 0) + fr] = 0;
            }

        // ---- PV: O[32 s][32 e] via 8 MFMAs ----
        floatx4 oacc[2][2] = {};
        #pragma unroll
        for (int ch = 0; ch < 2; ++ch) {
            short8 ap0 = *(const short8*)&Pb[fr * PSTR + ch * 32 + q4 * 8];
            short8 ap1 = *(const short8*)&Pb[(16 + fr) * PSTR + ch * 32 + q4 * 8];
            #pragma unroll
            for (int et = 0; et < 2; ++et) {
                short8 bv = *(const short8*)&Vt[(et * 16 + fr) * VTSTR + ch * 32 + q4 * 8];
                oacc[0][et] = __builtin_amdgcn_mfma_f32_16x16x32_bf16(ap0, bv, oacc[0][et], 0, 0, 0);
                oacc[1][et] = __builtin_amdgcn_mfma_f32_16x16x32_bf16(ap1, bv, oacc[1][et], 0, 0, 0);
            }
        }

        __syncthreads();   // (2) X(t) + scratch reads done everywhere

        // ---- write next tile's X (write-late half of the prefetch) ----
        if (PRE) {
            const int r = tid >> 3, seg = (tid & 7) * 32;
            unsigned short o[32];
            if (kv_ok) {
                #pragma unroll
                for (int j = 0; j < 32; ++j) o[j] = f2bf(pkv[j]);
            } else {
                #pragma unroll
                for (int j = 0; j < 32; ++j) o[j] = 0;
            }
            __builtin_memcpy(&Xkv[r * XSTR + seg], o, 64);
            if (tid < 256) {
                unsigned short o2[32];
                #pragma unroll
                for (int j = 0; j < 32; ++j) o2[j] = f2bf(pq[j]);
                __builtin_memcpy(&Xq[r * XSTR + seg], o2, 64);
            }
        }

        // ---- att tile [32][264] over scratch region ----
        #pragma unroll
        for (int it = 0; it < 2; ++it)
            #pragma unroll
            for (int et = 0; et < 2; ++et)
                #pragma unroll
                for (int reg = 0; reg < 4; ++reg)
                    As[it * 16 + q4 * 4 + reg][wv * 32 + et * 16 + fr] = f2bf(oacc[it][et][reg] * rs[it][reg]);

        __syncthreads();   // (3) att tile + next X complete

        // ---- output projection: out[32 x 256] = att @ Wo^T + bias2 ----
        floatx4 oa[2][2] = {};
        #pragma unroll
        for (int kc = 0; kc < 8; ++kc) {
            short8 ap0 = *(const short8*)&As[fr][kc * 32 + q4 * 8];
            short8 ap1 = *(const short8*)&As[16 + fr][kc * 32 + q4 * 8];
            #pragma unroll
            for (int j = 0; j < 2; ++j) {
                short8 bw = ldg8(Wo + ((wv * 2 + j) * 8 + kc) * 512);
                oa[0][j] = __builtin_amdgcn_mfma_f32_16x16x32_bf16(ap0, bw, oa[0][j], 0, 0, 0);
                oa[1][j] = __builtin_amdgcn_mfma_f32_16x16x32_bf16(ap1, bw, oa[1][j], 0, 0, 0);
            }
        }

        float* obase = out + (long)dir * 2097152 + ((long)b * 2048 + s0) * 256;
        #pragma unroll
        for (int it = 0; it < 2; ++it)
            #pragma unroll
            for (int j = 0; j < 2; ++j)
                #pragma unroll
                for (int reg = 0; reg < 4; ++reg)
                    obase[(it * 16 + q4 * 4 + reg) * 256 + wv * 32 + j * 16 + fr] = oa[it][j][reg] + bj2[j];

        __syncthreads();   // (4) As reads done -> next tile may overwrite scratch
    };

    body(sA, true,  sB);
    body(sB, false, 0);
}

// ---------- launch ----------
extern "C" void kernel_launch(void* const* d_in, const int* in_sizes, int n_in,
                              void* d_out, int out_size, void* d_ws, size_t ws_size,
                              hipStream_t stream)
{
    float* out = (float*)d_out;

    char* ws = (char*)d_ws;
    unsigned short* Wpack   = (unsigned short*)(ws + 0);          // 786432 B (frag-major)
    unsigned short* Wopack  = (unsigned short*)(ws + 786432);     // 262144 B (frag-major)
    float*          biasP   = (float*)(ws + 1048576);             // 6144 B
    float*          bias2   = (float*)(ws + 1054720);             // 2048 B

    repack_w<<<264, 256, 0, stream>>>(
        (const float*)d_in[2],  (const float*)d_in[3],
        (const float*)d_in[4],  (const float*)d_in[5],
        (const float*)d_in[6],  (const float*)d_in[7],
        (const float*)d_in[8],  (const float*)d_in[9],
        (const float*)d_in[10], (const float*)d_in[11],
        (const float*)d_in[12], (const float*)d_in[13],
        (const float*)d_in[14], (const float*)d_in[15],
        (const float*)d_in[16], (const float*)d_in[17],
        Wpack, Wopack, biasP, bias2);

    // fully fused QKV proj + windowed attention + output proj -> d_out (fp32)
    fused_attn<<<dim3(32, 4, 2), 512, 0, stream>>>(
        (const float*)d_in[0], (const float*)d_in[1],
        Wpack, biasP, Wopack, bias2, out);
}